// Round 14
// baseline (439.089 us; speedup 1.0000x reference)
//
#include <hip/hip_runtime.h>
#include <hip/hip_bf16.h>
#include <math.h>

#define N_NODES 10000
#define N_EDGES 20000
#define EPAD 20224
#define N_GRAPHS 64
#define DIM 64
#define NFEAT 32
#define EDIM 16
#define NCLS 10

static_assert(EPAD == 316 * 64, "EPAD");

typedef short short8 __attribute__((ext_vector_type(8)));
typedef float f32x16 __attribute__((ext_vector_type(16)));

static __device__ __forceinline__ short f2b(float f) {
  __hip_bfloat16 h = __float2bfloat16(f);
  return __builtin_bit_cast(short, h);
}

static __device__ __forceinline__ void gload_lds16(const void* g, void* s) {
  __builtin_amdgcn_global_load_lds(
      (const __attribute__((address_space(1))) unsigned int*)g,
      (__attribute__((address_space(3))) unsigned int*)s, 16, 0, 0);
}

// ---- k_pre: pack(1161) + ef+L0-mlp1(2500) + root0(2500) ----
// Pack (32x32x16 B-frag order): window S = 16 k-rows; short8 at
// [S*128 + n*64 + l] holds B[S*16 + (l>>5)*8 + u][n*32 + (l&31)].
__global__ __launch_bounds__(256) void k_pre(
    const float* __restrict__ ea, const float* __restrict__ etw,
    const float* __restrict__ etb, const float* __restrict__ nw1,
    const float* __restrict__ nb1, const float* __restrict__ x,
    const float* __restrict__ rootw, const float* __restrict__ rootb,
    const float* __restrict__ w20, const float* __restrict__ b20,
    const float* __restrict__ w2c, const float* __restrict__ b2c,
    float* __restrict__ h1T, float* __restrict__ agg,
    double* __restrict__ part0, short* __restrict__ pk,
    float* __restrict__ gpool) {
  const int b = blockIdx.x, t = threadIdx.x;
  if (b < 1161) {
    if (b == 0) { for (int i = t; i < N_GRAPHS * DIM; i += 256) gpool[i] = 0.f; }
    __shared__ float tile[32][65];
    const float *w2, *b2; short* out; int K, lb;
    if (b < 129) { w2 = w20; b2 = b20; out = pk; K = 4096; lb = b; }
    else {
      int bb = b - 129; int k = bb / 258; lb = bb % 258;
      w2 = w2c + (size_t)k * 8192 * 64; b2 = b2c + (size_t)k * 4096;
      out = pk + 264192 + (size_t)k * 528384; K = 8192;
    }
    #pragma unroll
    for (int it = 0; it < 2; ++it) {
      int idx = t + it * 256;
      int r = idx >> 4, c4 = idx & 15;
      int k = lb * 32 + r;
      const float* sp = (k < K) ? (w2 + (size_t)k * 64 + c4 * 4)
                                : (b2 + (size_t)(k - K) * 64 + c4 * 4);
      float4 v = *(const float4*)sp;
      float* dr = &tile[r][c4 * 4];
      dr[0] = v.x; dr[1] = v.y; dr[2] = v.z; dr[3] = v.w;
    }
    __syncthreads();
    const int S_local = t >> 7, n = (t >> 6) & 1, l = t & 63;
    const int rbase = S_local * 16 + ((l >> 5) << 3);
    const int col = n * 32 + (l & 31);
    short8 o;
    #pragma unroll
    for (int u = 0; u < 8; ++u) o[u] = f2b(tile[rbase + u][col]);
    ((short8*)out)[(size_t)lb * 256 + t] = o;
  } else if (b < 3661) {  // ---- e (LDS only) + L0 edge MLP -> h1T ----
    const int e0 = (b - 1161) * 8;
    __shared__ float sea[8][17];
    __shared__ float se[8][65];
    if (t < 128) {
      int r = t >> 4, c = t & 15;
      sea[r][c] = ea[(size_t)(e0 + r) * EDIM + c];
    }
    __syncthreads();
    {
      int o = t & 63, eh = t >> 6;
      #pragma unroll
      for (int k = 0; k < 2; ++k) {
        int r = eh * 2 + k;
        float a = etb[o];
        #pragma unroll
        for (int i = 0; i < EDIM; ++i) a = fmaf(sea[r][i], etw[i * 64 + o], a);
        se[r][o] = a;
      }
    }
    __syncthreads();
    {
      int j = t & 127, eh = t >> 7;
      int r0 = eh * 4;
      float a0 = nb1[j], a1 = a0, a2 = a0, a3 = a0;
      #pragma unroll 8
      for (int i = 0; i < 64; ++i) {
        float wv = nw1[i * 128 + j];
        a0 = fmaf(se[r0 + 0][i], wv, a0);
        a1 = fmaf(se[r0 + 1][i], wv, a1);
        a2 = fmaf(se[r0 + 2][i], wv, a2);
        a3 = fmaf(se[r0 + 3][i], wv, a3);
      }
      float4 o = {fmaxf(a0, 0.f), fmaxf(a1, 0.f), fmaxf(a2, 0.f), fmaxf(a3, 0.f)};
      *(float4*)(h1T + (size_t)j * EPAD + e0 + r0) = o;
    }
  } else {  // ---- root0 ----
    const int u = b - 3661;
    if (u == 0 && t < 128) part0[t] = 0.0;
    int idx = u * 256 + t;
    if (idx < N_NODES * DIM) {
      int n = idx >> 6, o = idx & 63;
      float a = rootb[o];
      const float* hr = x + (size_t)n * NFEAT;
      #pragma unroll 8
      for (int i = 0; i < NFEAT; ++i) a = fmaf(hr[i], rootw[i * 64 + o], a);
      agg[idx] = a;
    }
  }
}

// ---- implicit-A MFMA msg GEMM: 32x32x16, LDS-shared B, register h,
// 2-wave blocks for occupancy. grid 2528 flat: cy = bid&7, bx = bid>>3.
// Block = 2 waves x 32 edges = 64 edges; NC=8 chunks (JR=16).
template<int IN>
__global__ __launch_bounds__(128) void k_msg(
    const float* __restrict__ h1T, const float* __restrict__ xin,
    const int* __restrict__ src, const short* __restrict__ pk,
    float* __restrict__ pt) {
  constexpr int QW = IN / 16;            // 2 (L0) / 4
  constexpr int JR = 16;                 // j's per chunk
  constexpr int GB = QW * 2048;          // B bytes per j-group
  __shared__ __align__(16) short bbuf[3][QW * 1024];
  const int t = threadIdx.x, l = t & 63, w = t >> 6;   // w in {0,1}
  const int bid = blockIdx.x;
  const int cy = bid & 7;
  const int bx = bid >> 3;
  const int e0 = bx * 64;
  const int jbase = cy * JR;
  const int ng = JR + (cy == 0 ? 1 : 0);

  const char* pkc = (const char*)pk;
  const char* bias_gb = pkc + (size_t)(8 * IN) * 2048;

  auto stage = [&](int g) {
    const char* gb = (g < JR) ? pkc + (size_t)(jbase + g) * GB : bias_gb;
    #pragma unroll
    for (int s = 0; s < QW; ++s) {            // QW loads per wave (GB/2 bytes)
      int off = w * (GB / 2) + s * 1024;
      gload_lds16(gb + off + l * 16, (char*)&bbuf[g % 3][0] + off);
    }
  };

  const int ecol = e0 + w * 32 + (l & 31);
  auto ldh = [&](int g) -> float {            // dummy (row jbase) for bias group
    int j = (g < JR) ? (jbase + g) : jbase;
    return h1T[(size_t)j * EPAD + ecol];
  };

  // x fragments (whole-K resident): xr[q][u] = x[src[e]][q*16 + (l>>5)*8 + u]
  const int h8 = (l >> 5) << 3;
  const int srow = src[ecol < N_EDGES ? ecol : 0];
  float xr[QW][8];
  #pragma unroll
  for (int q = 0; q < QW; ++q) {
    const float* xp = xin + (size_t)srow * IN + q * 16 + h8;
    float4 a = *(const float4*)xp;
    float4 bq = *(const float4*)(xp + 4);
    xr[q][0] = a.x;  xr[q][1] = a.y;  xr[q][2] = a.z;  xr[q][3] = a.w;
    xr[q][4] = bq.x; xr[q][5] = bq.y; xr[q][6] = bq.z; xr[q][7] = bq.w;
  }

  asm volatile("s_waitcnt vmcnt(0) lgkmcnt(0)" ::: "memory");
  stage(0); float hE = ldh(0);
  stage(1); float hO = ldh(1);

  f32x16 acc0 = {}, acc1 = {};

  // Per group: wait(counted) -> barrier -> prefetch(g+2: QW stage + 1 h-load)
  // -> MFMA. Younger-ops count at wait = QW + 1 -> vmcnt(5)/vmcnt(3).
#define MSG_BODY(g, HREG)                                                     \
  {                                                                           \
    if ((g) + 1 < ng) {                                                       \
      if constexpr (QW == 4) asm volatile("s_waitcnt vmcnt(5)" ::: "memory"); \
      else                   asm volatile("s_waitcnt vmcnt(3)" ::: "memory"); \
    } else {                                                                  \
      asm volatile("s_waitcnt vmcnt(0)" ::: "memory");                        \
    }                                                                         \
    asm volatile("s_barrier" ::: "memory");                                   \
    float hm_ = ((g) < JR) ? HREG : 1.0f;                                     \
    if ((g) + 2 < ng) { stage((g) + 2); HREG = ldh((g) + 2); }                \
    const short8* bp_ = (const short8*)&bbuf[(g) % 3][0];                     \
    __builtin_amdgcn_s_setprio(1);                                            \
    _Pragma("unroll")                                                         \
    for (int q = 0; q < QW; ++q) {                                            \
      short8 b0_ = bp_[q * 128 + l];                                          \
      short8 b1_ = bp_[q * 128 + 64 + l];                                     \
      short8 av_;                                                             \
      _Pragma("unroll")                                                       \
      for (int u = 0; u < 8; ++u) av_[u] = f2b(hm_ * xr[q][u]);               \
      acc0 = __builtin_amdgcn_mfma_f32_32x32x16_bf16(av_, b0_, acc0, 0, 0, 0);\
      acc1 = __builtin_amdgcn_mfma_f32_32x32x16_bf16(av_, b1_, acc1, 0, 0, 0);\
    }                                                                         \
    __builtin_amdgcn_s_setprio(0);                                            \
  }

  for (int g = 0; g < ng; g += 2) {
    MSG_BODY(g, hE)
    if (g + 1 < ng) MSG_BODY(g + 1, hO)
  }
#undef MSG_BODY

  // C/D (m74/m101): col = lane&31, row = (v&3)+8*(v>>2)+4*(lane>>5)
  float* po = pt + ((size_t)cy * EPAD + e0 + w * 32) * 64 + (l & 31);
  #pragma unroll
  for (int v = 0; v < 16; ++v) {
    int r = (v & 3) + ((v >> 2) << 3) + ((l >> 5) << 2);
    po[(size_t)r * 64]      = acc0[v];
    po[(size_t)r * 64 + 32] = acc1[v];
  }
}

// ---- sum 8 chunk-partials, one atomicAdd per output element ----
__global__ __launch_bounds__(256) void k_reduce(const float* __restrict__ pt,
    const int* __restrict__ dst, float* __restrict__ agg) {
  int idx = blockIdx.x * 256 + threadIdx.x;
  int e = idx >> 4;
  if (e >= N_EDGES) return;
  int c = (idx & 15) << 2;
  const float* p = pt + (size_t)e * 64 + c;
  float4 a = *(const float4*)p;
  #pragma unroll
  for (int s = 1; s < 8; ++s) {
    float4 b = *(const float4*)(p + (size_t)s * EPAD * 64);
    a.x += b.x; a.y += b.y; a.z += b.z; a.w += b.w;
  }
  float* ap = agg + (size_t)dst[e] * 64 + c;
  atomicAdd(ap + 0, a.x);
  atomicAdd(ap + 1, a.y);
  atomicAdd(ap + 2, a.z);
  atomicAdd(ap + 3, a.w);
}

// ---- BN partial sums (coalesced, f64 atomics into part[0..127]) ----
__global__ __launch_bounds__(256) void k_bnpart(const float* __restrict__ agg,
    double* __restrict__ part) {
  const int t = threadIdx.x;
  const int c = t & 63, rg = t >> 6;
  const int r0 = blockIdx.x * 50;
  const int r1 = min(r0 + 50, N_NODES);
  double s = 0.0, s2 = 0.0;
  for (int r = r0 + rg; r < r1; r += 4) {
    float v = agg[(size_t)r * 64 + c];
    s += v;
    s2 += (double)v * v;
  }
  __shared__ double shs[4][64];
  __shared__ double shq[4][64];
  shs[rg][c] = s; shq[rg][c] = s2;
  __syncthreads();
  if (t < 64) {
    double ts = shs[0][t] + shs[1][t] + shs[2][t] + shs[3][t];
    double tq = shq[0][t] + shq[1][t] + shq[2][t] + shq[3][t];
    atomicAdd(&part[t], ts);
    atomicAdd(&part[64 + t], tq);
  }
}

// ---- fused: bnapply(k)[+resid]->h_cur; root(k+1)->agg (in-place);
//      mlp1(k+1)->h1T with e recomputed from edge_attr. ----
__global__ __launch_bounds__(256) void k_inter(
    float* __restrict__ agg, const double* __restrict__ part,
    const float* __restrict__ gamma, const float* __restrict__ beta,
    const float* resid, float* __restrict__ h_cur,
    const float* __restrict__ rootw, const float* __restrict__ rootb,
    double* __restrict__ partn,
    const float* __restrict__ ea, const float* __restrict__ etw,
    const float* __restrict__ etb, const float* __restrict__ w1,
    const float* __restrict__ b1, float* __restrict__ h1T) {
  const int b = blockIdx.x, t = threadIdx.x;
  if (b < 157) {
    __shared__ float sh[64][65];
    if (b == 0 && t < 128) partn[t] = 0.0;
    const int o = t & 63, rg = t >> 6;
    const int n0 = b * 64;
    float m = (float)(part[o] * (1.0 / N_NODES));
    float s2 = (float)(part[64 + o] * (1.0 / N_NODES));
    float inv = 1.0f / sqrtf(s2 - m * m + 1e-5f);
    float sc = gamma[o] * inv;
    float sf = beta[o] - m * sc;
    #pragma unroll
    for (int k = 0; k < 16; ++k) {
      int r = rg * 16 + k;
      int n = n0 + r;
      float v = 0.f;
      if (n < N_NODES) {
        v = fmaxf(fmaf(agg[(size_t)n * 64 + o], sc, sf), 0.f);
        if (resid) v += resid[(size_t)n * 64 + o];
        h_cur[(size_t)n * 64 + o] = v;
      }
      sh[r][o] = v;
    }
    __syncthreads();
    float acc[16];
    float rb = rootb[o];
    #pragma unroll
    for (int k = 0; k < 16; ++k) acc[k] = rb;
    for (int i = 0; i < 64; ++i) {
      float wv = rootw[i * 64 + o];
      #pragma unroll
      for (int k = 0; k < 16; ++k) acc[k] = fmaf(sh[rg * 16 + k][i], wv, acc[k]);
    }
    #pragma unroll
    for (int k = 0; k < 16; ++k) {
      int n = n0 + rg * 16 + k;
      if (n < N_NODES) agg[(size_t)n * 64 + o] = acc[k];
    }
  } else {
    const int e0 = (b - 157) * 8;
    __shared__ float sea[8][17];
    __shared__ float se[8][65];
    if (t < 128) {
      int r = t >> 4, c = t & 15;
      sea[r][c] = ea[(size_t)(e0 + r) * EDIM + c];
    }
    __syncthreads();
    {
      int o = t & 63, eh = t >> 6;
      #pragma unroll
      for (int k = 0; k < 2; ++k) {
        int r = eh * 2 + k;
        float a = etb[o];
        #pragma unroll
        for (int i = 0; i < EDIM; ++i) a = fmaf(sea[r][i], etw[i * 64 + o], a);
        se[r][o] = a;
      }
    }
    __syncthreads();
    {
      int j = t & 127, eh = t >> 7;
      int r0 = eh * 4;
      float a0 = b1[j], a1 = a0, a2 = a0, a3 = a0;
      #pragma unroll 8
      for (int i = 0; i < 64; ++i) {
        float wv = w1[i * 128 + j];
        a0 = fmaf(se[r0 + 0][i], wv, a0);
        a1 = fmaf(se[r0 + 1][i], wv, a1);
        a2 = fmaf(se[r0 + 2][i], wv, a2);
        a3 = fmaf(se[r0 + 3][i], wv, a3);
      }
      float4 o = {fmaxf(a0, 0.f), fmaxf(a1, 0.f), fmaxf(a2, 0.f), fmaxf(a3, 0.f)};
      *(float4*)(h1T + (size_t)j * EPAD + e0 + r0) = o;
    }
  }
}

// ---- final: bnapply(4) + resid + global_max_pool ----
__global__ __launch_bounds__(256) void k_final(const float* __restrict__ agg,
    const double* __restrict__ part, const float* __restrict__ gamma,
    const float* __restrict__ beta, const float* __restrict__ resid,
    const int* __restrict__ batch, float* __restrict__ gpool) {
  int idx = blockIdx.x * 256 + threadIdx.x;
  if (idx >= N_NODES * DIM) return;
  int c = idx & 63, r = idx >> 6;
  float m = (float)(part[c] * (1.0 / N_NODES));
  float s2 = (float)(part[64 + c] * (1.0 / N_NODES));
  float inv = 1.0f / sqrtf(s2 - m * m + 1e-5f);
  float sc = gamma[c] * inv;
  float sf = beta[c] - m * sc;
  float v = fmaxf(fmaf(agg[idx], sc, sf), 0.f) + resid[idx];
  atomicMax((unsigned int*)&gpool[batch[r] * 64 + c], __float_as_uint(v));
}

// ---- head: per-graph MLP chain ----
__global__ __launch_bounds__(64) void k_head(const float* __restrict__ g,
    const float* __restrict__ w1, const float* __restrict__ b1,
    const float* __restrict__ w2, const float* __restrict__ b2,
    const float* __restrict__ wo, const float* __restrict__ bo,
    float* __restrict__ out) {
  __shared__ float s0[64];
  __shared__ float s1[64];
  const int r = blockIdx.x, t = threadIdx.x;
  s0[t] = g[r * 64 + t];
  __syncthreads();
  float a = b1[t];
  #pragma unroll 8
  for (int i = 0; i < 64; ++i) a = fmaf(s0[i], w1[i * 64 + t], a);
  s1[t] = fmaxf(a, 0.f);
  __syncthreads();
  a = b2[t];
  #pragma unroll 8
  for (int i = 0; i < 64; ++i) a = fmaf(s1[i], w2[i * 64 + t], a);
  __syncthreads();
  s0[t] = fmaxf(a, 0.f);
  __syncthreads();
  if (t < NCLS) {
    float o = bo[t];
    #pragma unroll 8
    for (int i = 0; i < 64; ++i) o = fmaf(s0[i], wo[i * NCLS + t], o);
    out[r * NCLS + t] = 1.f / (1.f + expf(-o));
  }
}

extern "C" void kernel_launch(void* const* d_in, const int* in_sizes, int n_in,
                              void* d_out, int out_size, void* d_ws, size_t ws_size,
                              hipStream_t stream) {
  const float* x          = (const float*)d_in[0];
  const int*   eidx       = (const int*)d_in[1];
  const float* eattr      = (const float*)d_in[2];
  const int*   batch      = (const int*)d_in[3];
  const float* et_w       = (const float*)d_in[4];
  const float* et_b       = (const float*)d_in[5];
  const float* nn1_w1     = (const float*)d_in[6];
  const float* nn1_b1     = (const float*)d_in[7];
  const float* nn1_w2     = (const float*)d_in[8];
  const float* nn1_b2     = (const float*)d_in[9];
  const float* root_in    = (const float*)d_in[10];
  const float* bias_in    = (const float*)d_in[11];
  const float* convs_w1   = (const float*)d_in[12];
  const float* convs_b1   = (const float*)d_in[13];
  const float* convs_w2   = (const float*)d_in[14];
  const float* convs_b2   = (const float*)d_in[15];
  const float* convs_root = (const float*)d_in[16];
  const float* convs_bias = (const float*)d_in[17];
  const float* bn_gamma   = (const float*)d_in[18];
  const float* bn_beta    = (const float*)d_in[19];
  const float* lin1_w     = (const float*)d_in[20];
  const float* lin1_b     = (const float*)d_in[21];
  const float* lin2_w     = (const float*)d_in[22];
  const float* lin2_b     = (const float*)d_in[23];
  const float* lout_w     = (const float*)d_in[24];
  const float* lout_b     = (const float*)d_in[25];

  const int* srcp = eidx;
  const int* dstp = eidx + N_EDGES;

  char* wsb = (char*)d_ws;
  double* part0 = (double*)wsb;                          // 1 KB
  double* part1 = (double*)(wsb + 1024);                 // 1 KB
  float* h1T    = (float*)(wsb + 4096);                  // 128*EPAD f32 (10.35 MB)
  float* agg    = h1T + 128 * EPAD;                      // 2.56 MB
  float* h_cur  = agg + N_NODES * 64;                    // 2.56 MB
  float* g      = h_cur + N_NODES * 64;                  // 16 KB
  short* pk0    = (short*)(g + N_GRAPHS * 64);           // 4.76 MB
  short* pkL[4];
  for (int k = 0; k < 4; ++k) pkL[k] = pk0 + 264192 + (size_t)k * 528384;
  float* pt     = (float*)(pk0 + 264192 + 4 * 528384);   // 8*EPAD*64 f32 (41.4 MB)
  double* parts[2] = {part0, part1};

  k_pre<<<6161, 256, 0, stream>>>(eattr, et_w, et_b, nn1_w1, nn1_b1, x,
                                  root_in, bias_in, nn1_w2, nn1_b2,
                                  convs_w2, convs_b2, h1T, agg, part0, pk0, g);

  k_msg<32><<<2528, 128, 0, stream>>>(h1T, x, srcp, pk0, pt);
  k_reduce<<<(EPAD * 16) / 256, 256, 0, stream>>>(pt, dstp, agg);
  k_bnpart<<<200, 256, 0, stream>>>(agg, part0);

  for (int k = 0; k < 4; ++k) {
    k_inter<<<2657, 256, 0, stream>>>(
        agg, parts[k & 1], bn_gamma + k * 64, bn_beta + k * 64,
        (k == 0) ? nullptr : h_cur, h_cur,
        convs_root + (size_t)k * 4096, convs_bias + (size_t)k * 64,
        parts[(k + 1) & 1],
        eattr, et_w, et_b,
        convs_w1 + (size_t)k * 8192, convs_b1 + (size_t)k * 128, h1T);
    k_msg<64><<<2528, 128, 0, stream>>>(h1T, h_cur, srcp, pkL[k], pt);
    k_reduce<<<(EPAD * 16) / 256, 256, 0, stream>>>(pt, dstp, agg);
    k_bnpart<<<200, 256, 0, stream>>>(agg, parts[(k + 1) & 1]);
  }

  k_final<<<2500, 256, 0, stream>>>(agg, parts[0], bn_gamma + 4 * 64,
                                    bn_beta + 4 * 64, h_cur, batch, g);
  k_head<<<N_GRAPHS, 64, 0, stream>>>(g, lin1_w, lin1_b, lin2_w, lin2_b,
                                      lout_w, lout_b, (float*)d_out);
}

// Round 15
// 433.306 us; speedup vs baseline: 1.0133x; 1.0133x over previous
//
#include <hip/hip_runtime.h>
#include <hip/hip_bf16.h>
#include <math.h>

#define N_NODES 10000
#define N_EDGES 20000
#define EPAD 20224
#define N_GRAPHS 64
#define DIM 64
#define NFEAT 32
#define EDIM 16
#define NCLS 10

static_assert(EPAD == 316 * 64, "EPAD");

typedef short short8 __attribute__((ext_vector_type(8)));
typedef float f32x4 __attribute__((ext_vector_type(4)));

static __device__ __forceinline__ short f2b(float f) {
  __hip_bfloat16 h = __float2bfloat16(f);
  return __builtin_bit_cast(short, h);
}

static __device__ __forceinline__ void gload_lds16(const void* g, void* s) {
  __builtin_amdgcn_global_load_lds(
      (const __attribute__((address_space(1))) unsigned int*)g,
      (__attribute__((address_space(3))) unsigned int*)s, 16, 0, 0);
}

// ---- k_pre: pack(1161) + ef+L0-mlp1(2500) + root0(2500) ----
// Pack (16x16x32 B-frag order): window S = 32 k-rows; short8 at
// [S*256 + n*64 + l] holds B[S*32 + (l>>4)*8 + u][n*16 + (l&15)], n in 0..3.
__global__ __launch_bounds__(256) void k_pre(
    const float* __restrict__ ea, const float* __restrict__ etw,
    const float* __restrict__ etb, const float* __restrict__ nw1,
    const float* __restrict__ nb1, const float* __restrict__ x,
    const float* __restrict__ rootw, const float* __restrict__ rootb,
    const float* __restrict__ w20, const float* __restrict__ b20,
    const float* __restrict__ w2c, const float* __restrict__ b2c,
    float* __restrict__ h1T, float* __restrict__ agg,
    double* __restrict__ part0, short* __restrict__ pk,
    float* __restrict__ gpool) {
  const int b = blockIdx.x, t = threadIdx.x;
  if (b < 1161) {  // ---- pack w2+b2: one 32-row window per block ----
    if (b == 0) { for (int i = t; i < N_GRAPHS * DIM; i += 256) gpool[i] = 0.f; }
    __shared__ float tile[32][65];
    const float *w2, *b2; short* out; int K, lb;
    if (b < 129) { w2 = w20; b2 = b20; out = pk; K = 4096; lb = b; }
    else {
      int bb = b - 129; int k = bb / 258; lb = bb % 258;
      w2 = w2c + (size_t)k * 8192 * 64; b2 = b2c + (size_t)k * 4096;
      out = pk + 264192 + (size_t)k * 528384; K = 8192;
    }
    #pragma unroll
    for (int it = 0; it < 2; ++it) {
      int idx = t + it * 256;
      int r = idx >> 4, c4 = idx & 15;
      int k = lb * 32 + r;
      const float* sp = (k < K) ? (w2 + (size_t)k * 64 + c4 * 4)
                                : (b2 + (size_t)(k - K) * 64 + c4 * 4);
      float4 v = *(const float4*)sp;
      float* dr = &tile[r][c4 * 4];
      dr[0] = v.x; dr[1] = v.y; dr[2] = v.z; dr[3] = v.w;
    }
    __syncthreads();
    const int n = t >> 6, l = t & 63;
    const int klo = (l >> 4) << 3;
    const int col = n * 16 + (l & 15);
    short8 o;
    #pragma unroll
    for (int u = 0; u < 8; ++u) o[u] = f2b(tile[klo + u][col]);
    ((short8*)out)[(size_t)lb * 256 + t] = o;
  } else if (b < 3661) {  // ---- e (LDS only) + L0 edge MLP -> h1T ----
    const int e0 = (b - 1161) * 8;
    __shared__ float sea[8][17];
    __shared__ float se[8][65];
    if (t < 128) {
      int r = t >> 4, c = t & 15;
      sea[r][c] = ea[(size_t)(e0 + r) * EDIM + c];
    }
    __syncthreads();
    {
      int o = t & 63, eh = t >> 6;
      #pragma unroll
      for (int k = 0; k < 2; ++k) {
        int r = eh * 2 + k;
        float a = etb[o];
        #pragma unroll
        for (int i = 0; i < EDIM; ++i) a = fmaf(sea[r][i], etw[i * 64 + o], a);
        se[r][o] = a;
      }
    }
    __syncthreads();
    {
      int j = t & 127, eh = t >> 7;
      int r0 = eh * 4;
      float a0 = nb1[j], a1 = a0, a2 = a0, a3 = a0;
      #pragma unroll 8
      for (int i = 0; i < 64; ++i) {
        float wv = nw1[i * 128 + j];
        a0 = fmaf(se[r0 + 0][i], wv, a0);
        a1 = fmaf(se[r0 + 1][i], wv, a1);
        a2 = fmaf(se[r0 + 2][i], wv, a2);
        a3 = fmaf(se[r0 + 3][i], wv, a3);
      }
      float4 o = {fmaxf(a0, 0.f), fmaxf(a1, 0.f), fmaxf(a2, 0.f), fmaxf(a3, 0.f)};
      *(float4*)(h1T + (size_t)j * EPAD + e0 + r0) = o;
    }
  } else {  // ---- root0 ----
    const int u = b - 3661;
    if (u == 0 && t < 128) part0[t] = 0.0;
    int idx = u * 256 + t;
    if (idx < N_NODES * DIM) {
      int n = idx >> 6, o = idx & 63;
      float a = rootb[o];
      const float* hr = x + (size_t)n * NFEAT;
      #pragma unroll 8
      for (int i = 0; i < NFEAT; ++i) a = fmaf(hr[i], rootw[i * 64 + o], a);
      agg[idx] = a;
    }
  }
}

// ---- implicit-A MFMA msg GEMM: 16x16x32, LDS-shared B, 3-buf counted vmcnt ----
// flat grid 1264: cy = bid&3 (K-chunk; fixed per XCD), bx = bid>>2 (edge tile).
// block = 4 waves x 16 edges = 64 edges; chunk = K/4 (JR=32 j's).
template<int IN>
__global__ __launch_bounds__(256, 4) void k_msg(
    const float* __restrict__ h1T, const float* __restrict__ xin,
    const int* __restrict__ src, const short* __restrict__ pk,
    float* __restrict__ pt) {
  constexpr int NW = IN / 32;            // K=32 windows per j: 1 (L0) / 2
  constexpr int JR = 32;                 // j's per chunk (128/4)
  constexpr int JB = IN * 128;           // B bytes per j (NW*4096)
  __shared__ float sh_h[JR][64];
  __shared__ __align__(16) short bbuf[3][IN * 64];
  const int t = threadIdx.x, l = t & 63, w = t >> 6;
  const int bid = blockIdx.x;
  const int cy = bid & 3;
  const int bx = bid >> 2;
  const int e0 = bx * 64;
  const int jbase = cy * JR;
  const int ng = JR + (cy == 0 ? 1 : 0);

  const char* pkc = (const char*)pk;
  const char* bias_gb = pkc + (size_t)IN * 16384;  // after 4*IN main windows

  auto stage = [&](int g) {
    const char* gb = (g < JR) ? pkc + (size_t)(jbase + g) * JB : bias_gb;
    #pragma unroll
    for (int s = 0; s < NW; ++s) {
      int off = w * (IN * 32) + s * 1024;
      gload_lds16(gb + off + l * 16, (char*)&bbuf[g % 3][0] + off);
    }
  };

  // stage h tile [JR][64]: 16 lanes x float4 per row (conflict-free)
  #pragma unroll
  for (int it = 0; it < 2; ++it) {
    int u = t + it * 256;
    int row = u >> 4, c4 = u & 15;
    float4 v = *(const float4*)(h1T + (size_t)(jbase + row) * EPAD + e0 + c4 * 4);
    *(float4*)&sh_h[row][c4 * 4] = v;
  }

  // x fragments (whole-K resident): xr[q][u] = x[src[e]][q*32 + (l>>4)*8 + u]
  const int i8 = (l >> 4) << 3;
  const int eme = e0 + w * 16 + (l & 15);
  const int srow = src[eme < N_EDGES ? eme : 0];
  float xr[NW][8];
  #pragma unroll
  for (int q = 0; q < NW; ++q) {
    const float* xp = xin + (size_t)srow * IN + q * 32 + i8;
    float4 a = *(const float4*)xp;
    float4 bq = *(const float4*)(xp + 4);
    xr[q][0] = a.x;  xr[q][1] = a.y;  xr[q][2] = a.z;  xr[q][3] = a.w;
    xr[q][4] = bq.x; xr[q][5] = bq.y; xr[q][6] = bq.z; xr[q][7] = bq.w;
  }

  asm volatile("s_waitcnt vmcnt(0) lgkmcnt(0)" ::: "memory");
  stage(0);
  if (ng > 1) stage(1);

  f32x4 acc0 = {}, acc1 = {}, acc2 = {}, acc3 = {};

  for (int g = 0; g < ng; ++g) {
    if (g + 1 < ng) {  // g's loads landed; g+1's NW still in flight
      if constexpr (NW == 2) asm volatile("s_waitcnt vmcnt(2)" ::: "memory");
      else                   asm volatile("s_waitcnt vmcnt(1)" ::: "memory");
    } else {
      asm volatile("s_waitcnt vmcnt(0)" ::: "memory");
    }
    asm volatile("s_barrier" ::: "memory");
    if (g + 2 < ng) stage(g + 2);
    const short8* bp = (const short8*)&bbuf[g % 3][0];
    if (g < JR) {
      float hv = sh_h[g][w * 16 + (l & 15)];
      __builtin_amdgcn_s_setprio(1);
      #pragma unroll
      for (int q = 0; q < NW; ++q) {
        short8 av;
        #pragma unroll
        for (int u = 0; u < 8; ++u) av[u] = f2b(hv * xr[q][u]);
        acc0 = __builtin_amdgcn_mfma_f32_16x16x32_bf16(av, bp[(q*4+0)*64 + l], acc0, 0, 0, 0);
        acc1 = __builtin_amdgcn_mfma_f32_16x16x32_bf16(av, bp[(q*4+1)*64 + l], acc1, 0, 0, 0);
        acc2 = __builtin_amdgcn_mfma_f32_16x16x32_bf16(av, bp[(q*4+2)*64 + l], acc2, 0, 0, 0);
        acc3 = __builtin_amdgcn_mfma_f32_16x16x32_bf16(av, bp[(q*4+3)*64 + l], acc3, 0, 0, 0);
      }
      __builtin_amdgcn_s_setprio(0);
    } else {  // bias rows: A = x directly
      __builtin_amdgcn_s_setprio(1);
      #pragma unroll
      for (int q = 0; q < NW; ++q) {
        short8 av;
        #pragma unroll
        for (int u = 0; u < 8; ++u) av[u] = f2b(xr[q][u]);
        acc0 = __builtin_amdgcn_mfma_f32_16x16x32_bf16(av, bp[(q*4+0)*64 + l], acc0, 0, 0, 0);
        acc1 = __builtin_amdgcn_mfma_f32_16x16x32_bf16(av, bp[(q*4+1)*64 + l], acc1, 0, 0, 0);
        acc2 = __builtin_amdgcn_mfma_f32_16x16x32_bf16(av, bp[(q*4+2)*64 + l], acc2, 0, 0, 0);
        acc3 = __builtin_amdgcn_mfma_f32_16x16x32_bf16(av, bp[(q*4+3)*64 + l], acc3, 0, 0, 0);
      }
      __builtin_amdgcn_s_setprio(0);
    }
  }

  // C/D (m89/m91): col = lane&15, row = (lane>>4)*4 + v
  float* po = pt + ((size_t)cy * EPAD + e0 + w * 16) * 64 + (l & 15);
  #pragma unroll
  for (int v = 0; v < 4; ++v) {
    int r = ((l >> 4) << 2) + v;
    po[(size_t)r * 64 +  0] = acc0[v];
    po[(size_t)r * 64 + 16] = acc1[v];
    po[(size_t)r * 64 + 32] = acc2[v];
    po[(size_t)r * 64 + 48] = acc3[v];
  }
}

// ---- sum 4 chunk-partials, one atomicAdd per output element ----
__global__ __launch_bounds__(256) void k_reduce(const float* __restrict__ pt,
    const int* __restrict__ dst, float* __restrict__ agg) {
  int idx = blockIdx.x * 256 + threadIdx.x;
  int e = idx >> 4;
  if (e >= N_EDGES) return;
  int c = (idx & 15) << 2;
  const float* p = pt + (size_t)e * 64 + c;
  float4 a = *(const float4*)p;
  #pragma unroll
  for (int s = 1; s < 4; ++s) {
    float4 b = *(const float4*)(p + (size_t)s * EPAD * 64);
    a.x += b.x; a.y += b.y; a.z += b.z; a.w += b.w;
  }
  float* ap = agg + (size_t)dst[e] * 64 + c;
  atomicAdd(ap + 0, a.x);
  atomicAdd(ap + 1, a.y);
  atomicAdd(ap + 2, a.z);
  atomicAdd(ap + 3, a.w);
}

// ---- BN partial sums (coalesced, f64 atomics into part[0..127]) ----
__global__ __launch_bounds__(256) void k_bnpart(const float* __restrict__ agg,
    double* __restrict__ part) {
  const int t = threadIdx.x;
  const int c = t & 63, rg = t >> 6;
  const int r0 = blockIdx.x * 50;
  const int r1 = min(r0 + 50, N_NODES);
  double s = 0.0, s2 = 0.0;
  for (int r = r0 + rg; r < r1; r += 4) {
    float v = agg[(size_t)r * 64 + c];
    s += v;
    s2 += (double)v * v;
  }
  __shared__ double shs[4][64];
  __shared__ double shq[4][64];
  shs[rg][c] = s; shq[rg][c] = s2;
  __syncthreads();
  if (t < 64) {
    double ts = shs[0][t] + shs[1][t] + shs[2][t] + shs[3][t];
    double tq = shq[0][t] + shq[1][t] + shq[2][t] + shq[3][t];
    atomicAdd(&part[t], ts);
    atomicAdd(&part[64 + t], tq);
  }
}

// ---- fused: bnapply(k)[+resid]->h_cur; root(k+1)->agg (in-place);
//      mlp1(k+1)->h1T with e recomputed from edge_attr. ----
__global__ __launch_bounds__(256) void k_inter(
    float* __restrict__ agg, const double* __restrict__ part,
    const float* __restrict__ gamma, const float* __restrict__ beta,
    const float* resid, float* __restrict__ h_cur,
    const float* __restrict__ rootw, const float* __restrict__ rootb,
    double* __restrict__ partn,
    const float* __restrict__ ea, const float* __restrict__ etw,
    const float* __restrict__ etb, const float* __restrict__ w1,
    const float* __restrict__ b1, float* __restrict__ h1T) {
  const int b = blockIdx.x, t = threadIdx.x;
  if (b < 157) {
    __shared__ float sh[64][65];
    if (b == 0 && t < 128) partn[t] = 0.0;
    const int o = t & 63, rg = t >> 6;
    const int n0 = b * 64;
    float m = (float)(part[o] * (1.0 / N_NODES));
    float s2 = (float)(part[64 + o] * (1.0 / N_NODES));
    float inv = 1.0f / sqrtf(s2 - m * m + 1e-5f);
    float sc = gamma[o] * inv;
    float sf = beta[o] - m * sc;
    #pragma unroll
    for (int k = 0; k < 16; ++k) {
      int r = rg * 16 + k;
      int n = n0 + r;
      float v = 0.f;
      if (n < N_NODES) {
        v = fmaxf(fmaf(agg[(size_t)n * 64 + o], sc, sf), 0.f);
        if (resid) v += resid[(size_t)n * 64 + o];
        h_cur[(size_t)n * 64 + o] = v;
      }
      sh[r][o] = v;
    }
    __syncthreads();
    float acc[16];
    float rb = rootb[o];
    #pragma unroll
    for (int k = 0; k < 16; ++k) acc[k] = rb;
    for (int i = 0; i < 64; ++i) {
      float wv = rootw[i * 64 + o];
      #pragma unroll
      for (int k = 0; k < 16; ++k) acc[k] = fmaf(sh[rg * 16 + k][i], wv, acc[k]);
    }
    #pragma unroll
    for (int k = 0; k < 16; ++k) {
      int n = n0 + rg * 16 + k;
      if (n < N_NODES) agg[(size_t)n * 64 + o] = acc[k];
    }
  } else {
    const int e0 = (b - 157) * 8;
    __shared__ float sea[8][17];
    __shared__ float se[8][65];
    if (t < 128) {
      int r = t >> 4, c = t & 15;
      sea[r][c] = ea[(size_t)(e0 + r) * EDIM + c];
    }
    __syncthreads();
    {
      int o = t & 63, eh = t >> 6;
      #pragma unroll
      for (int k = 0; k < 2; ++k) {
        int r = eh * 2 + k;
        float a = etb[o];
        #pragma unroll
        for (int i = 0; i < EDIM; ++i) a = fmaf(sea[r][i], etw[i * 64 + o], a);
        se[r][o] = a;
      }
    }
    __syncthreads();
    {
      int j = t & 127, eh = t >> 7;
      int r0 = eh * 4;
      float a0 = b1[j], a1 = a0, a2 = a0, a3 = a0;
      #pragma unroll 8
      for (int i = 0; i < 64; ++i) {
        float wv = w1[i * 128 + j];
        a0 = fmaf(se[r0 + 0][i], wv, a0);
        a1 = fmaf(se[r0 + 1][i], wv, a1);
        a2 = fmaf(se[r0 + 2][i], wv, a2);
        a3 = fmaf(se[r0 + 3][i], wv, a3);
      }
      float4 o = {fmaxf(a0, 0.f), fmaxf(a1, 0.f), fmaxf(a2, 0.f), fmaxf(a3, 0.f)};
      *(float4*)(h1T + (size_t)j * EPAD + e0 + r0) = o;
    }
  }
}

// ---- final: bnapply(4) + resid + global_max_pool ----
__global__ __launch_bounds__(256) void k_final(const float* __restrict__ agg,
    const double* __restrict__ part, const float* __restrict__ gamma,
    const float* __restrict__ beta, const float* __restrict__ resid,
    const int* __restrict__ batch, float* __restrict__ gpool) {
  int idx = blockIdx.x * 256 + threadIdx.x;
  if (idx >= N_NODES * DIM) return;
  int c = idx & 63, r = idx >> 6;
  float m = (float)(part[c] * (1.0 / N_NODES));
  float s2 = (float)(part[64 + c] * (1.0 / N_NODES));
  float inv = 1.0f / sqrtf(s2 - m * m + 1e-5f);
  float sc = gamma[c] * inv;
  float sf = beta[c] - m * sc;
  float v = fmaxf(fmaf(agg[idx], sc, sf), 0.f) + resid[idx];
  atomicMax((unsigned int*)&gpool[batch[r] * 64 + c], __float_as_uint(v));
}

// ---- head: per-graph MLP chain ----
__global__ __launch_bounds__(64) void k_head(const float* __restrict__ g,
    const float* __restrict__ w1, const float* __restrict__ b1,
    const float* __restrict__ w2, const float* __restrict__ b2,
    const float* __restrict__ wo, const float* __restrict__ bo,
    float* __restrict__ out) {
  __shared__ float s0[64];
  __shared__ float s1[64];
  const int r = blockIdx.x, t = threadIdx.x;
  s0[t] = g[r * 64 + t];
  __syncthreads();
  float a = b1[t];
  #pragma unroll 8
  for (int i = 0; i < 64; ++i) a = fmaf(s0[i], w1[i * 64 + t], a);
  s1[t] = fmaxf(a, 0.f);
  __syncthreads();
  a = b2[t];
  #pragma unroll 8
  for (int i = 0; i < 64; ++i) a = fmaf(s1[i], w2[i * 64 + t], a);
  __syncthreads();
  s0[t] = fmaxf(a, 0.f);
  __syncthreads();
  if (t < NCLS) {
    float o = bo[t];
    #pragma unroll 8
    for (int i = 0; i < 64; ++i) o = fmaf(s0[i], wo[i * NCLS + t], o);
    out[r * NCLS + t] = 1.f / (1.f + expf(-o));
  }
}

extern "C" void kernel_launch(void* const* d_in, const int* in_sizes, int n_in,
                              void* d_out, int out_size, void* d_ws, size_t ws_size,
                              hipStream_t stream) {
  const float* x          = (const float*)d_in[0];
  const int*   eidx       = (const int*)d_in[1];
  const float* eattr      = (const float*)d_in[2];
  const int*   batch      = (const int*)d_in[3];
  const float* et_w       = (const float*)d_in[4];
  const float* et_b       = (const float*)d_in[5];
  const float* nn1_w1     = (const float*)d_in[6];
  const float* nn1_b1     = (const float*)d_in[7];
  const float* nn1_w2     = (const float*)d_in[8];
  const float* nn1_b2     = (const float*)d_in[9];
  const float* root_in    = (const float*)d_in[10];
  const float* bias_in    = (const float*)d_in[11];
  const float* convs_w1   = (const float*)d_in[12];
  const float* convs_b1   = (const float*)d_in[13];
  const float* convs_w2   = (const float*)d_in[14];
  const float* convs_b2   = (const float*)d_in[15];
  const float* convs_root = (const float*)d_in[16];
  const float* convs_bias = (const float*)d_in[17];
  const float* bn_gamma   = (const float*)d_in[18];
  const float* bn_beta    = (const float*)d_in[19];
  const float* lin1_w     = (const float*)d_in[20];
  const float* lin1_b     = (const float*)d_in[21];
  const float* lin2_w     = (const float*)d_in[22];
  const float* lin2_b     = (const float*)d_in[23];
  const float* lout_w     = (const float*)d_in[24];
  const float* lout_b     = (const float*)d_in[25];

  const int* srcp = eidx;
  const int* dstp = eidx + N_EDGES;

  char* wsb = (char*)d_ws;
  double* part0 = (double*)wsb;                          // 1 KB
  double* part1 = (double*)(wsb + 1024);                 // 1 KB
  float* h1T    = (float*)(wsb + 4096);                  // 128*EPAD f32 (10.35 MB)
  float* agg    = h1T + 128 * EPAD;                      // 2.56 MB
  float* h_cur  = agg + N_NODES * 64;                    // 2.56 MB
  float* g      = h_cur + N_NODES * 64;                  // 16 KB
  short* pk0    = (short*)(g + N_GRAPHS * 64);           // 4.76 MB
  short* pkL[4];
  for (int k = 0; k < 4; ++k) pkL[k] = pk0 + 264192 + (size_t)k * 528384;
  float* pt     = (float*)(pk0 + 264192 + 4 * 528384);   // 4*EPAD*64 f32 (20.7 MB)
  double* parts[2] = {part0, part1};

  k_pre<<<6161, 256, 0, stream>>>(eattr, et_w, et_b, nn1_w1, nn1_b1, x,
                                  root_in, bias_in, nn1_w2, nn1_b2,
                                  convs_w2, convs_b2, h1T, agg, part0, pk0, g);

  k_msg<32><<<1264, 256, 0, stream>>>(h1T, x, srcp, pk0, pt);
  k_reduce<<<(EPAD * 16) / 256, 256, 0, stream>>>(pt, dstp, agg);
  k_bnpart<<<200, 256, 0, stream>>>(agg, part0);

  for (int k = 0; k < 4; ++k) {
    k_inter<<<2657, 256, 0, stream>>>(
        agg, parts[k & 1], bn_gamma + k * 64, bn_beta + k * 64,
        (k == 0) ? nullptr : h_cur, h_cur,
        convs_root + (size_t)k * 4096, convs_bias + (size_t)k * 64,
        parts[(k + 1) & 1],
        eattr, et_w, et_b,
        convs_w1 + (size_t)k * 8192, convs_b1 + (size_t)k * 128, h1T);
    k_msg<64><<<1264, 256, 0, stream>>>(h1T, h_cur, srcp, pkL[k], pt);
    k_reduce<<<(EPAD * 16) / 256, 256, 0, stream>>>(pt, dstp, agg);
    k_bnpart<<<200, 256, 0, stream>>>(agg, parts[(k + 1) & 1]);
  }

  k_final<<<2500, 256, 0, stream>>>(agg, parts[0], bn_gamma + 4 * 64,
                                    bn_beta + 4 * 64, h_cur, batch, g);
  k_head<<<N_GRAPHS, 64, 0, stream>>>(g, lin1_w, lin1_b, lin2_w, lin2_b,
                                      lout_w, lout_b, (float*)d_out);
}

// Round 16
// 392.845 us; speedup vs baseline: 1.1177x; 1.1030x over previous
//
#include <hip/hip_runtime.h>
#include <hip/hip_bf16.h>
#include <math.h>

#define N_NODES 10000
#define N_EDGES 20000
#define EPAD 20224
#define N_GRAPHS 64
#define DIM 64
#define NFEAT 32
#define EDIM 16
#define NCLS 10

static_assert(EPAD == 316 * 64, "EPAD");

typedef short short8 __attribute__((ext_vector_type(8)));
typedef float f32x4 __attribute__((ext_vector_type(4)));

static __device__ __forceinline__ short f2b(float f) {
  __hip_bfloat16 h = __float2bfloat16(f);
  return __builtin_bit_cast(short, h);
}

static __device__ __forceinline__ void gload_lds16(const void* g, void* s) {
  __builtin_amdgcn_global_load_lds(
      (const __attribute__((address_space(1))) unsigned int*)g,
      (__attribute__((address_space(3))) unsigned int*)s, 16, 0, 0);
}

// ---- k_pre: pack(1161) + ef+L0-mlp1(2500) + root0(2500) ----
// Pack (16x16x32 B-frag order): window S = 32 k-rows; short8 at
// [S*256 + n*64 + l] holds B[S*32 + (l>>4)*8 + u][n*16 + (l&15)], n in 0..3.
__global__ __launch_bounds__(256) void k_pre(
    const float* __restrict__ ea, const float* __restrict__ etw,
    const float* __restrict__ etb, const float* __restrict__ nw1,
    const float* __restrict__ nb1, const float* __restrict__ x,
    const float* __restrict__ rootw, const float* __restrict__ rootb,
    const float* __restrict__ w20, const float* __restrict__ b20,
    const float* __restrict__ w2c, const float* __restrict__ b2c,
    float* __restrict__ h1T, float* __restrict__ agg,
    double* __restrict__ part0, short* __restrict__ pk,
    float* __restrict__ gpool) {
  const int b = blockIdx.x, t = threadIdx.x;
  if (b < 1161) {  // ---- pack w2+b2: one 32-row window per block ----
    if (b == 0) { for (int i = t; i < N_GRAPHS * DIM; i += 256) gpool[i] = 0.f; }
    __shared__ float tile[32][65];
    const float *w2, *b2; short* out; int K, lb;
    if (b < 129) { w2 = w20; b2 = b20; out = pk; K = 4096; lb = b; }
    else {
      int bb = b - 129; int k = bb / 258; lb = bb % 258;
      w2 = w2c + (size_t)k * 8192 * 64; b2 = b2c + (size_t)k * 4096;
      out = pk + 264192 + (size_t)k * 528384; K = 8192;
    }
    #pragma unroll
    for (int it = 0; it < 2; ++it) {
      int idx = t + it * 256;
      int r = idx >> 4, c4 = idx & 15;
      int k = lb * 32 + r;
      const float* sp = (k < K) ? (w2 + (size_t)k * 64 + c4 * 4)
                                : (b2 + (size_t)(k - K) * 64 + c4 * 4);
      float4 v = *(const float4*)sp;
      float* dr = &tile[r][c4 * 4];
      dr[0] = v.x; dr[1] = v.y; dr[2] = v.z; dr[3] = v.w;
    }
    __syncthreads();
    const int n = t >> 6, l = t & 63;
    const int klo = (l >> 4) << 3;
    const int col = n * 16 + (l & 15);
    short8 o;
    #pragma unroll
    for (int u = 0; u < 8; ++u) o[u] = f2b(tile[klo + u][col]);
    ((short8*)out)[(size_t)lb * 256 + t] = o;
  } else if (b < 3661) {  // ---- e (LDS only) + L0 edge MLP -> h1T ----
    const int e0 = (b - 1161) * 8;
    __shared__ float sea[8][17];
    __shared__ float se[8][65];
    if (t < 128) {
      int r = t >> 4, c = t & 15;
      sea[r][c] = ea[(size_t)(e0 + r) * EDIM + c];
    }
    __syncthreads();
    {
      int o = t & 63, eh = t >> 6;
      #pragma unroll
      for (int k = 0; k < 2; ++k) {
        int r = eh * 2 + k;
        float a = etb[o];
        #pragma unroll
        for (int i = 0; i < EDIM; ++i) a = fmaf(sea[r][i], etw[i * 64 + o], a);
        se[r][o] = a;
      }
    }
    __syncthreads();
    {
      int j = t & 127, eh = t >> 7;
      int r0 = eh * 4;
      float a0 = nb1[j], a1 = a0, a2 = a0, a3 = a0;
      #pragma unroll 8
      for (int i = 0; i < 64; ++i) {
        float wv = nw1[i * 128 + j];
        a0 = fmaf(se[r0 + 0][i], wv, a0);
        a1 = fmaf(se[r0 + 1][i], wv, a1);
        a2 = fmaf(se[r0 + 2][i], wv, a2);
        a3 = fmaf(se[r0 + 3][i], wv, a3);
      }
      float4 o = {fmaxf(a0, 0.f), fmaxf(a1, 0.f), fmaxf(a2, 0.f), fmaxf(a3, 0.f)};
      *(float4*)(h1T + (size_t)j * EPAD + e0 + r0) = o;
    }
  } else {  // ---- root0 ----
    const int u = b - 3661;
    if (u == 0 && t < 128) part0[t] = 0.0;
    int idx = u * 256 + t;
    if (idx < N_NODES * DIM) {
      int n = idx >> 6, o = idx & 63;
      float a = rootb[o];
      const float* hr = x + (size_t)n * NFEAT;
      #pragma unroll 8
      for (int i = 0; i < NFEAT; ++i) a = fmaf(hr[i], rootw[i * 64 + o], a);
      agg[idx] = a;
    }
  }
}

// ---- implicit-A MFMA msg GEMM: 16x16x32, LDS-shared B, 3-buf counted vmcnt,
// direct atomicAdd into agg (no pt, no reduce kernel).
// flat grid 1264: cy = bid&3 (K-chunk), bx = bid>>2 (edge tile).
// block = 4 waves x 16 edges = 64 edges; chunk = K/4 (JR=32 j's).
template<int IN>
__global__ __launch_bounds__(256, 4) void k_msg(
    const float* __restrict__ h1T, const float* __restrict__ xin,
    const int* __restrict__ src, const int* __restrict__ dst,
    const short* __restrict__ pk, float* __restrict__ agg) {
  constexpr int NW = IN / 32;            // K=32 windows per j: 1 (L0) / 2
  constexpr int JR = 32;                 // j's per chunk (128/4)
  constexpr int JB = IN * 128;           // B bytes per j (NW*4096)
  __shared__ float sh_h[JR][64];
  __shared__ __align__(16) short bbuf[3][IN * 64];
  const int t = threadIdx.x, l = t & 63, w = t >> 6;
  const int bid = blockIdx.x;
  const int cy = bid & 3;
  const int bx = bid >> 2;
  const int e0 = bx * 64;
  const int jbase = cy * JR;
  const int ng = JR + (cy == 0 ? 1 : 0);

  const char* pkc = (const char*)pk;
  const char* bias_gb = pkc + (size_t)IN * 16384;  // after 4*IN main windows

  auto stage = [&](int g) {
    const char* gb = (g < JR) ? pkc + (size_t)(jbase + g) * JB : bias_gb;
    #pragma unroll
    for (int s = 0; s < NW; ++s) {
      int off = w * (IN * 32) + s * 1024;
      gload_lds16(gb + off + l * 16, (char*)&bbuf[g % 3][0] + off);
    }
  };

  // stage h tile [JR][64]: 16 lanes x float4 per row (conflict-free)
  #pragma unroll
  for (int it = 0; it < 2; ++it) {
    int u = t + it * 256;
    int row = u >> 4, c4 = u & 15;
    float4 v = *(const float4*)(h1T + (size_t)(jbase + row) * EPAD + e0 + c4 * 4);
    *(float4*)&sh_h[row][c4 * 4] = v;
  }

  // x fragments (whole-K resident): xr[q][u] = x[src[e]][q*32 + (l>>4)*8 + u]
  const int i8 = (l >> 4) << 3;
  const int eme = e0 + w * 16 + (l & 15);
  const int srow = src[eme < N_EDGES ? eme : 0];
  float xr[NW][8];
  #pragma unroll
  for (int q = 0; q < NW; ++q) {
    const float* xp = xin + (size_t)srow * IN + q * 32 + i8;
    float4 a = *(const float4*)xp;
    float4 bq = *(const float4*)(xp + 4);
    xr[q][0] = a.x;  xr[q][1] = a.y;  xr[q][2] = a.z;  xr[q][3] = a.w;
    xr[q][4] = bq.x; xr[q][5] = bq.y; xr[q][6] = bq.z; xr[q][7] = bq.w;
  }

  asm volatile("s_waitcnt vmcnt(0) lgkmcnt(0)" ::: "memory");
  stage(0);
  if (ng > 1) stage(1);

  f32x4 acc0 = {}, acc1 = {}, acc2 = {}, acc3 = {};

  for (int g = 0; g < ng; ++g) {
    if (g + 1 < ng) {  // g's loads landed; g+1's NW still in flight
      if constexpr (NW == 2) asm volatile("s_waitcnt vmcnt(2)" ::: "memory");
      else                   asm volatile("s_waitcnt vmcnt(1)" ::: "memory");
    } else {
      asm volatile("s_waitcnt vmcnt(0)" ::: "memory");
    }
    asm volatile("s_barrier" ::: "memory");
    if (g + 2 < ng) stage(g + 2);
    const short8* bp = (const short8*)&bbuf[g % 3][0];
    if (g < JR) {
      float hv = sh_h[g][w * 16 + (l & 15)];
      __builtin_amdgcn_s_setprio(1);
      #pragma unroll
      for (int q = 0; q < NW; ++q) {
        short8 av;
        #pragma unroll
        for (int u = 0; u < 8; ++u) av[u] = f2b(hv * xr[q][u]);
        acc0 = __builtin_amdgcn_mfma_f32_16x16x32_bf16(av, bp[(q*4+0)*64 + l], acc0, 0, 0, 0);
        acc1 = __builtin_amdgcn_mfma_f32_16x16x32_bf16(av, bp[(q*4+1)*64 + l], acc1, 0, 0, 0);
        acc2 = __builtin_amdgcn_mfma_f32_16x16x32_bf16(av, bp[(q*4+2)*64 + l], acc2, 0, 0, 0);
        acc3 = __builtin_amdgcn_mfma_f32_16x16x32_bf16(av, bp[(q*4+3)*64 + l], acc3, 0, 0, 0);
      }
      __builtin_amdgcn_s_setprio(0);
    } else {  // bias rows: A = x directly
      __builtin_amdgcn_s_setprio(1);
      #pragma unroll
      for (int q = 0; q < NW; ++q) {
        short8 av;
        #pragma unroll
        for (int u = 0; u < 8; ++u) av[u] = f2b(xr[q][u]);
        acc0 = __builtin_amdgcn_mfma_f32_16x16x32_bf16(av, bp[(q*4+0)*64 + l], acc0, 0, 0, 0);
        acc1 = __builtin_amdgcn_mfma_f32_16x16x32_bf16(av, bp[(q*4+1)*64 + l], acc1, 0, 0, 0);
        acc2 = __builtin_amdgcn_mfma_f32_16x16x32_bf16(av, bp[(q*4+2)*64 + l], acc2, 0, 0, 0);
        acc3 = __builtin_amdgcn_mfma_f32_16x16x32_bf16(av, bp[(q*4+3)*64 + l], acc3, 0, 0, 0);
      }
      __builtin_amdgcn_s_setprio(0);
    }
  }

  // C/D (m89/m91): col = lane&15, row = (lane>>4)*4 + v.
  // Direct scatter: one atomicAdd per output element per chunk (agg L2-resident).
  #pragma unroll
  for (int v = 0; v < 4; ++v) {
    int r = ((l >> 4) << 2) + v;
    int e2 = e0 + w * 16 + r;
    if (e2 < N_EDGES) {
      float* ap = agg + (size_t)dst[e2] * 64 + (l & 15);
      atomicAdd(ap +  0, acc0[v]);
      atomicAdd(ap + 16, acc1[v]);
      atomicAdd(ap + 32, acc2[v]);
      atomicAdd(ap + 48, acc3[v]);
    }
  }
}

// ---- BN partial sums (coalesced, f64 atomics into part[0..127]) ----
__global__ __launch_bounds__(256) void k_bnpart(const float* __restrict__ agg,
    double* __restrict__ part) {
  const int t = threadIdx.x;
  const int c = t & 63, rg = t >> 6;
  const int r0 = blockIdx.x * 50;
  const int r1 = min(r0 + 50, N_NODES);
  double s = 0.0, s2 = 0.0;
  for (int r = r0 + rg; r < r1; r += 4) {
    float v = agg[(size_t)r * 64 + c];
    s += v;
    s2 += (double)v * v;
  }
  __shared__ double shs[4][64];
  __shared__ double shq[4][64];
  shs[rg][c] = s; shq[rg][c] = s2;
  __syncthreads();
  if (t < 64) {
    double ts = shs[0][t] + shs[1][t] + shs[2][t] + shs[3][t];
    double tq = shq[0][t] + shq[1][t] + shq[2][t] + shq[3][t];
    atomicAdd(&part[t], ts);
    atomicAdd(&part[64 + t], tq);
  }
}

// ---- fused: bnapply(k)[+resid]->h_cur; root(k+1)->agg (in-place);
//      mlp1(k+1)->h1T with e recomputed from edge_attr. ----
__global__ __launch_bounds__(256) void k_inter(
    float* __restrict__ agg, const double* __restrict__ part,
    const float* __restrict__ gamma, const float* __restrict__ beta,
    const float* resid, float* __restrict__ h_cur,
    const float* __restrict__ rootw, const float* __restrict__ rootb,
    double* __restrict__ partn,
    const float* __restrict__ ea, const float* __restrict__ etw,
    const float* __restrict__ etb, const float* __restrict__ w1,
    const float* __restrict__ b1, float* __restrict__ h1T) {
  const int b = blockIdx.x, t = threadIdx.x;
  if (b < 157) {
    __shared__ float sh[64][65];
    if (b == 0 && t < 128) partn[t] = 0.0;
    const int o = t & 63, rg = t >> 6;
    const int n0 = b * 64;
    float m = (float)(part[o] * (1.0 / N_NODES));
    float s2 = (float)(part[64 + o] * (1.0 / N_NODES));
    float inv = 1.0f / sqrtf(s2 - m * m + 1e-5f);
    float sc = gamma[o] * inv;
    float sf = beta[o] - m * sc;
    #pragma unroll
    for (int k = 0; k < 16; ++k) {
      int r = rg * 16 + k;
      int n = n0 + r;
      float v = 0.f;
      if (n < N_NODES) {
        v = fmaxf(fmaf(agg[(size_t)n * 64 + o], sc, sf), 0.f);
        if (resid) v += resid[(size_t)n * 64 + o];
        h_cur[(size_t)n * 64 + o] = v;
      }
      sh[r][o] = v;
    }
    __syncthreads();
    float acc[16];
    float rb = rootb[o];
    #pragma unroll
    for (int k = 0; k < 16; ++k) acc[k] = rb;
    for (int i = 0; i < 64; ++i) {
      float wv = rootw[i * 64 + o];
      #pragma unroll
      for (int k = 0; k < 16; ++k) acc[k] = fmaf(sh[rg * 16 + k][i], wv, acc[k]);
    }
    #pragma unroll
    for (int k = 0; k < 16; ++k) {
      int n = n0 + rg * 16 + k;
      if (n < N_NODES) agg[(size_t)n * 64 + o] = acc[k];
    }
  } else {
    const int e0 = (b - 157) * 8;
    __shared__ float sea[8][17];
    __shared__ float se[8][65];
    if (t < 128) {
      int r = t >> 4, c = t & 15;
      sea[r][c] = ea[(size_t)(e0 + r) * EDIM + c];
    }
    __syncthreads();
    {
      int o = t & 63, eh = t >> 6;
      #pragma unroll
      for (int k = 0; k < 2; ++k) {
        int r = eh * 2 + k;
        float a = etb[o];
        #pragma unroll
        for (int i = 0; i < EDIM; ++i) a = fmaf(sea[r][i], etw[i * 64 + o], a);
        se[r][o] = a;
      }
    }
    __syncthreads();
    {
      int j = t & 127, eh = t >> 7;
      int r0 = eh * 4;
      float a0 = b1[j], a1 = a0, a2 = a0, a3 = a0;
      #pragma unroll 8
      for (int i = 0; i < 64; ++i) {
        float wv = w1[i * 128 + j];
        a0 = fmaf(se[r0 + 0][i], wv, a0);
        a1 = fmaf(se[r0 + 1][i], wv, a1);
        a2 = fmaf(se[r0 + 2][i], wv, a2);
        a3 = fmaf(se[r0 + 3][i], wv, a3);
      }
      float4 o = {fmaxf(a0, 0.f), fmaxf(a1, 0.f), fmaxf(a2, 0.f), fmaxf(a3, 0.f)};
      *(float4*)(h1T + (size_t)j * EPAD + e0 + r0) = o;
    }
  }
}

// ---- final: bnapply(4) + resid + global_max_pool ----
__global__ __launch_bounds__(256) void k_final(const float* __restrict__ agg,
    const double* __restrict__ part, const float* __restrict__ gamma,
    const float* __restrict__ beta, const float* __restrict__ resid,
    const int* __restrict__ batch, float* __restrict__ gpool) {
  int idx = blockIdx.x * 256 + threadIdx.x;
  if (idx >= N_NODES * DIM) return;
  int c = idx & 63, r = idx >> 6;
  float m = (float)(part[c] * (1.0 / N_NODES));
  float s2 = (float)(part[64 + c] * (1.0 / N_NODES));
  float inv = 1.0f / sqrtf(s2 - m * m + 1e-5f);
  float sc = gamma[c] * inv;
  float sf = beta[c] - m * sc;
  float v = fmaxf(fmaf(agg[idx], sc, sf), 0.f) + resid[idx];
  atomicMax((unsigned int*)&gpool[batch[r] * 64 + c], __float_as_uint(v));
}

// ---- head: per-graph MLP chain ----
__global__ __launch_bounds__(64) void k_head(const float* __restrict__ g,
    const float* __restrict__ w1, const float* __restrict__ b1,
    const float* __restrict__ w2, const float* __restrict__ b2,
    const float* __restrict__ wo, const float* __restrict__ bo,
    float* __restrict__ out) {
  __shared__ float s0[64];
  __shared__ float s1[64];
  const int r = blockIdx.x, t = threadIdx.x;
  s0[t] = g[r * 64 + t];
  __syncthreads();
  float a = b1[t];
  #pragma unroll 8
  for (int i = 0; i < 64; ++i) a = fmaf(s0[i], w1[i * 64 + t], a);
  s1[t] = fmaxf(a, 0.f);
  __syncthreads();
  a = b2[t];
  #pragma unroll 8
  for (int i = 0; i < 64; ++i) a = fmaf(s1[i], w2[i * 64 + t], a);
  __syncthreads();
  s0[t] = fmaxf(a, 0.f);
  __syncthreads();
  if (t < NCLS) {
    float o = bo[t];
    #pragma unroll 8
    for (int i = 0; i < 64; ++i) o = fmaf(s0[i], wo[i * NCLS + t], o);
    out[r * NCLS + t] = 1.f / (1.f + expf(-o));
  }
}

extern "C" void kernel_launch(void* const* d_in, const int* in_sizes, int n_in,
                              void* d_out, int out_size, void* d_ws, size_t ws_size,
                              hipStream_t stream) {
  const float* x          = (const float*)d_in[0];
  const int*   eidx       = (const int*)d_in[1];
  const float* eattr      = (const float*)d_in[2];
  const int*   batch      = (const int*)d_in[3];
  const float* et_w       = (const float*)d_in[4];
  const float* et_b       = (const float*)d_in[5];
  const float* nn1_w1     = (const float*)d_in[6];
  const float* nn1_b1     = (const float*)d_in[7];
  const float* nn1_w2     = (const float*)d_in[8];
  const float* nn1_b2     = (const float*)d_in[9];
  const float* root_in    = (const float*)d_in[10];
  const float* bias_in    = (const float*)d_in[11];
  const float* convs_w1   = (const float*)d_in[12];
  const float* convs_b1   = (const float*)d_in[13];
  const float* convs_w2   = (const float*)d_in[14];
  const float* convs_b2   = (const float*)d_in[15];
  const float* convs_root = (const float*)d_in[16];
  const float* convs_bias = (const float*)d_in[17];
  const float* bn_gamma   = (const float*)d_in[18];
  const float* bn_beta    = (const float*)d_in[19];
  const float* lin1_w     = (const float*)d_in[20];
  const float* lin1_b     = (const float*)d_in[21];
  const float* lin2_w     = (const float*)d_in[22];
  const float* lin2_b     = (const float*)d_in[23];
  const float* lout_w     = (const float*)d_in[24];
  const float* lout_b     = (const float*)d_in[25];

  const int* srcp = eidx;
  const int* dstp = eidx + N_EDGES;

  char* wsb = (char*)d_ws;
  double* part0 = (double*)wsb;                          // 1 KB
  double* part1 = (double*)(wsb + 1024);                 // 1 KB
  float* h1T    = (float*)(wsb + 4096);                  // 128*EPAD f32 (10.35 MB)
  float* agg    = h1T + 128 * EPAD;                      // 2.56 MB
  float* h_cur  = agg + N_NODES * 64;                    // 2.56 MB
  float* g      = h_cur + N_NODES * 64;                  // 16 KB
  short* pk0    = (short*)(g + N_GRAPHS * 64);           // 4.76 MB
  short* pkL[4];
  for (int k = 0; k < 4; ++k) pkL[k] = pk0 + 264192 + (size_t)k * 528384;
  double* parts[2] = {part0, part1};

  k_pre<<<6161, 256, 0, stream>>>(eattr, et_w, et_b, nn1_w1, nn1_b1, x,
                                  root_in, bias_in, nn1_w2, nn1_b2,
                                  convs_w2, convs_b2, h1T, agg, part0, pk0, g);

  k_msg<32><<<1264, 256, 0, stream>>>(h1T, x, srcp, dstp, pk0, agg);
  k_bnpart<<<200, 256, 0, stream>>>(agg, part0);

  for (int k = 0; k < 4; ++k) {
    k_inter<<<2657, 256, 0, stream>>>(
        agg, parts[k & 1], bn_gamma + k * 64, bn_beta + k * 64,
        (k == 0) ? nullptr : h_cur, h_cur,
        convs_root + (size_t)k * 4096, convs_bias + (size_t)k * 64,
        parts[(k + 1) & 1],
        eattr, et_w, et_b,
        convs_w1 + (size_t)k * 8192, convs_b1 + (size_t)k * 128, h1T);
    k_msg<64><<<1264, 256, 0, stream>>>(h1T, h_cur, srcp, dstp, pkL[k], agg);
    k_bnpart<<<200, 256, 0, stream>>>(agg, parts[(k + 1) & 1]);
  }

  k_final<<<2500, 256, 0, stream>>>(agg, parts[0], bn_gamma + 4 * 64,
                                    bn_beta + 4 * 64, h_cur, batch, g);
  k_head<<<N_GRAPHS, 64, 0, stream>>>(g, lin1_w, lin1_b, lin2_w, lin2_b,
                                      lout_w, lout_b, (float*)d_out);
}